// Round 3
// baseline (161.770 us; speedup 1.0000x reference)
//
#include <hip/hip_runtime.h>

// Tile: 16 output rows x 64 output cols; 4 tiles per (n,c); grid 16384.
// R3: block 256 -> 512 threads; per-thread streams halved in every stage.
//   S0 load -> S1 V-up(x2) -> S2 [H-up + act + H-down] fused -> S4 V-down + store.
//   s_in[26 x 80] : input rows gy0-5..gy0+20, cols -5..74 zero-padded   (bufA)
//   t1  [42 x 80] : vertical x2 up, cols 0..73 valid                    (bufB)
//   t3  [42 x 72] : H-up+act+H-down result, cols 0..63 valid            (bufA)
// LDS = (3024 + 3376 + 24)*4 ~= 25.7 KB; occupancy = 4 blocks/CU (wave-limited,
// 32 waves/CU vs 24 at 256 threads).
// S1: 518 items = 74 cols x 7 m-groups (3 m each), ~58 ops/thread (was 111).
// S2: 504 thr = 42 rows x 12 half-chunks (6 out cols each), ~280 ops (was 465).
// S4: 512 thr = 64 cols x 8 chunks (2 out rows each), ~42 ops (was 75).
#define SIN 80
#define ST1 80
#define ST3 72

__global__ __launch_bounds__(512, 8)
void synth_fused(const float* __restrict__ x, const float* __restrict__ bias,
                 const float* __restrict__ fu, const float* __restrict__ fd,
                 float* __restrict__ out)
{
    __shared__ __align__(16) float bufA[3024];
    __shared__ __align__(16) float bufB[3376];   // t1 42x80 + slack (reads to row41 col81)
    __shared__ float sfilt[24];
    float* const s_in = bufA;
    float* const s_t3 = bufA;
    float* const s_t1 = bufB;

    const int tid  = threadIdx.x;
    const int bx   = blockIdx.x;
    const int tile = bx & 3;
    const int nc   = bx >> 2;
    const int gy0  = tile << 4;

    if (tid < 24) sfilt[tid] = (tid < 12) ? fu[tid] : fd[tid - 12];
    const float bc = bias[nc & 511];
    const float* __restrict__ xc = x + ((size_t)nc << 12);

    // ---- S0: load 26 rows x 64 cols (float4, coalesced) + zero pad cols ----
    if (tid < 416) {                             // 26 rows * 16 float4
        int r  = tid >> 4;
        int c4 = (tid & 15) << 2;
        int gy = gy0 - 5 + r;
        float4 v = make_float4(0.f, 0.f, 0.f, 0.f);
        if ((unsigned)gy < 64u)
            v = *reinterpret_cast<const float4*>(xc + (gy << 6) + c4);
        float* dst = s_in + r * SIN + 5 + c4;
        dst[0] = v.x; dst[1] = v.y; dst[2] = v.z; dst[3] = v.w;
    }
    if (tid < 416) {                             // 26*16 pad slots (cols 0..4, 69..79)
        int r  = tid >> 4;
        int pc = tid & 15;
        int c  = (pc < 5) ? pc : (64 + pc);
        s_in[r * SIN + c] = 0.0f;
    }
    __syncthreads();

    float u[12], g[12];
    #pragma unroll
    for (int k = 0; k < 12; ++k) u[k] = sfilt[k];
    #pragma unroll
    for (int k = 0; k < 12; ++k) g[k] = sfilt[23 - k];   // g[k] = fd[11-k]

    // ---- S1: vertical x2 up. 518 items = 7 m-groups (3 m's each) x 74 cols ----
    // item (mg,c): t1 rows 6mg..6mg+5 at col c from s_in rows 3mg..3mg+7
    #pragma unroll
    for (int it = 0; it < 2; ++it) {
        int idx = tid + (it << 9);
        if (idx < 518) {
            const int mg = idx / 74;
            const int c  = idx - 74 * mg;
            const float* ip = s_in + (3 * mg) * SIN + c;
            float rv[8];
            #pragma unroll
            for (int j = 0; j < 8; ++j) rv[j] = ip[j * SIN];
            float* op = s_t1 + (6 * mg) * ST1 + c;
            #pragma unroll
            for (int m = 0; m < 3; ++m) {
                float aE = u[10]*rv[m];
                aE = fmaf(u[8], rv[m+1], aE); aE = fmaf(u[6], rv[m+2], aE);
                aE = fmaf(u[4], rv[m+3], aE); aE = fmaf(u[2], rv[m+4], aE);
                aE = fmaf(u[0], rv[m+5], aE);
                float aO = u[11]*rv[m];
                aO = fmaf(u[9], rv[m+1], aO); aO = fmaf(u[7], rv[m+2], aO);
                aO = fmaf(u[5], rv[m+3], aO); aO = fmaf(u[3], rv[m+4], aO);
                aO = fmaf(u[1], rv[m+5], aO);
                op[(2*m) * ST1]     = aE;
                op[(2*m + 1) * ST1] = aO;
            }
        }
    }
    __syncthreads();

    // fold the x4 up-gain into the up taps (only H-stage applies gain, once)
    #pragma unroll
    for (int k = 0; k < 12; ++k) u[k] *= 4.0f;

    // ---- S2: fused H-up + bias/lrelu*sqrt2/clamp + H-down ----
    // 504 threads = 42 rows x 12 chunks; chunk h owns out cols 6h..6h+5.
    // t2L[mL] = act( sum_j u[10+(mL&1)-2j]*wL[(mL>>1)+j] + bc ), mL 0..21,
    //   wL[s] = t1[r][6h+s], s 0..15
    // t3[r][6h+i] = sum_k g[k]*t2L[2i+k], i 0..5
    // h=11: reads t1 cols up to 81 (slack), writes t3 cols 66..71 (pad).
    if (tid < 504) {
        const int r = tid / 12;
        const int h = tid - 12 * r;
        const float* t1r = s_t1 + r * ST1 + 6 * h;
        float w[16];
        #pragma unroll
        for (int j = 0; j < 8; ++j) {
            float2 v2 = *reinterpret_cast<const float2*>(t1r + 2 * j);
            w[2*j] = v2.x; w[2*j+1] = v2.y;
        }
        const float P = 0.84852813742385703f;   // 0.6*sqrt2
        const float Q = 0.56568542494923802f;   // 0.4*sqrt2
        float t2v[22];
        #pragma unroll
        for (int i = 0; i < 11; ++i) {
            float zE = fmaf(u[10], w[i], bc);
            zE = fmaf(u[8], w[i+1], zE); zE = fmaf(u[6], w[i+2], zE);
            zE = fmaf(u[4], w[i+3], zE); zE = fmaf(u[2], w[i+4], zE);
            zE = fmaf(u[0], w[i+5], zE);
            float zO = fmaf(u[11], w[i], bc);
            zO = fmaf(u[9], w[i+1], zO); zO = fmaf(u[7], w[i+2], zO);
            zO = fmaf(u[5], w[i+3], zO); zO = fmaf(u[3], w[i+4], zO);
            zO = fmaf(u[1], w[i+5], zO);
            float vE = fmaf(Q, __builtin_fabsf(zE), P * zE);
            float vO = fmaf(Q, __builtin_fabsf(zO), P * zO);
            t2v[2*i]   = __builtin_amdgcn_fmed3f(vE, -256.0f, 256.0f);
            t2v[2*i+1] = __builtin_amdgcn_fmed3f(vO, -256.0f, 256.0f);
        }
        float* t3r = s_t3 + r * ST3 + 6 * h;
        #pragma unroll
        for (int i = 0; i < 3; ++i) {
            float2 o2;
            #pragma unroll
            for (int s = 0; s < 2; ++s) {
                const int oi = 2 * i + s;
                float acc = g[0] * t2v[2*oi];
                #pragma unroll
                for (int k = 1; k < 12; ++k) acc = fmaf(g[k], t2v[2*oi + k], acc);
                (&o2.x)[s] = acc;
            }
            *reinterpret_cast<float2*>(t3r + 2 * i) = o2;
        }
    }
    __syncthreads();

    // ---- S4: vertical /2 down. 512 threads = 64 cols x 8 chunks (2 out rows) ----
    // out rows gy0+2rc, gy0+2rc+1 at col c; reads t3 rows 4rc..4rc+13
    {
        const int c  = tid & 63;
        const int rc = tid >> 6;
        const float* t3c = s_t3 + (rc << 2) * ST3 + c;
        float wv[14];
        #pragma unroll
        for (int j = 0; j < 14; ++j) wv[j] = t3c[j * ST3];
        float* op = out + ((size_t)nc << 12) + ((size_t)(gy0 + (rc << 1)) << 6) + c;
        #pragma unroll
        for (int s = 0; s < 2; ++s) {
            float acc = g[0] * wv[2*s];
            #pragma unroll
            for (int k = 1; k < 12; ++k) acc = fmaf(g[k], wv[2*s + k], acc);
            op[(size_t)(s << 6)] = acc;
        }
    }
}

extern "C" void kernel_launch(void* const* d_in, const int* in_sizes, int n_in,
                              void* d_out, int out_size, void* d_ws, size_t ws_size,
                              hipStream_t stream) {
    const float* x    = (const float*)d_in[0];
    const float* bias = (const float*)d_in[1];
    const float* fu   = (const float*)d_in[2];
    const float* fd   = (const float*)d_in[3];
    float* out        = (float*)d_out;

    dim3 grid(8 * 512 * 4);   // (n*c) x 4 row-tiles of 16x64
    dim3 block(512);
    hipLaunchKernelGGL(synth_fused, grid, block, 0, stream, x, bias, fu, fd, out);
}

// Round 5
// 151.431 us; speedup vs baseline: 1.0683x; 1.0683x over previous
//
#include <hip/hip_runtime.h>

// Tile: 16 output rows x 64 output cols; 4 tiles per (n,c); grid 16384.
// R5: R4 retry (R4 was a macro/braced-init compile error; logic unchanged).
//     R2 structure (best: 75us) + packed-fp32 (v_pk_fma_f32 via v2f/elementwise
//     builtins) in all FIR chains + sqrt2 folded into H-up taps (act = 3 ops).
//   S0 load -> S1 V-up(x2) -> S2 [H-up + act + H-down] fused -> S4 V-down + store.
//   s_in[26 x 80] : input rows gy0-5..gy0+20, cols -5..74 zero-padded   (bufA)
//   t1  [42 x 80] : vertical x2 up, cols 0..73 valid                    (bufB)
//   t3  [42 x 72] : H-up+act+H-down result, cols 0..63 valid            (bufA)
// LDS = (3024 + 3376 + 24)*4 ~= 25.7 KB.
// Pairing scheme:
//   up-chains:   acc2={even,odd phase}, coeff pairs {u[10-2j],u[11-2j]}, data broadcast
//   down-chains: acc2={even,odd tap partials}, coeff pairs {g[2j],g[2j+1]},
//                data = adjacent pairs (stride-2 downsample => natural LDS pairs),
//                result = acc2.x + acc2.y
#define SIN 80
#define ST1 80
#define ST3 72

typedef float v2f __attribute__((ext_vector_type(2)));

static __device__ __forceinline__ v2f fma2(v2f a, v2f b, v2f c) {
    return __builtin_elementwise_fma(a, b, c);
}
static __device__ __forceinline__ v2f bcast2(float s) {
    v2f r; r.x = s; r.y = s; return r;
}
static __device__ __forceinline__ v2f mk2(float a, float b) {
    v2f r; r.x = a; r.y = b; return r;
}

__global__ __launch_bounds__(256, 4)
void synth_fused(const float* __restrict__ x, const float* __restrict__ bias,
                 const float* __restrict__ fu, const float* __restrict__ fd,
                 float* __restrict__ out)
{
    __shared__ __align__(16) float bufA[3024];
    __shared__ __align__(16) float bufB[3376];   // t1 42x80 + slack (q=5 reads to +21)
    __shared__ float sfilt[24];
    float* const s_in = bufA;
    float* const s_t3 = bufA;
    float* const s_t1 = bufB;

    const int tid  = threadIdx.x;
    const int bx   = blockIdx.x;
    const int tile = bx & 3;
    const int nc   = bx >> 2;
    const int gy0  = tile << 4;

    if (tid < 24) sfilt[tid] = (tid < 12) ? fu[tid] : fd[tid - 12];
    const float bc = bias[nc & 511];
    const float* __restrict__ xc = x + ((size_t)nc << 12);

    // ---- S0: load 26 rows x 64 cols (float4, coalesced) + zero pad cols ----
    #pragma unroll
    for (int it = 0; it < 2; ++it) {
        int idx = tid + it * 256;
        if (idx < 416) {                         // 26 rows * 16 float4
            int r  = idx >> 4;
            int c4 = (idx & 15) << 2;
            int gy = gy0 - 5 + r;
            float4 v = make_float4(0.f, 0.f, 0.f, 0.f);
            if ((unsigned)gy < 64u)
                v = *reinterpret_cast<const float4*>(xc + (gy << 6) + c4);
            float* dst = s_in + r * SIN + 5 + c4;
            dst[0] = v.x; dst[1] = v.y; dst[2] = v.z; dst[3] = v.w;
        }
    }
    #pragma unroll
    for (int it = 0; it < 2; ++it) {                 // 26*16 pad slots (cols 0..4, 69..79)
        int idx = tid + it * 256;
        if (idx < 416) {
            int r  = idx >> 4;
            int pc = idx & 15;
            int c  = (pc < 5) ? pc : (64 + pc);
            s_in[r * SIN + c] = 0.0f;
        }
    }
    __syncthreads();

    // coefficient PAIRS
    v2f upk[6], gpk[6];
    #pragma unroll
    for (int j = 0; j < 6; ++j) {
        upk[j] = mk2(sfilt[10 - 2*j], sfilt[11 - 2*j]);   // {even,odd} up phases
        gpk[j] = mk2(sfilt[23 - 2*j], sfilt[22 - 2*j]);   // {g[2j], g[2j+1]}
    }

    // ---- S1: vertical x2 up, 1 col/thread. 222 threads (g3 0..2, c 0..73) ----
    // {t1[2m][c], t1[2m+1][c]} = sum_j upk[j] * {s_in[m+j][c]}bcast
    if (tid < 222) {
        const int g3 = tid / 74;
        const int c  = tid - 74 * g3;
        const float* ip = s_in + (7 * g3) * SIN + c;
        float rv[12];
        #pragma unroll
        for (int j = 0; j < 12; ++j) rv[j] = ip[j * SIN];
        float* op = s_t1 + (14 * g3) * ST1 + c;
        #pragma unroll
        for (int m = 0; m < 7; ++m) {
            v2f acc = upk[0] * bcast2(rv[m]);
            #pragma unroll
            for (int j = 1; j < 6; ++j)
                acc = fma2(upk[j], bcast2(rv[m + j]), acc);
            op[(2*m) * ST1]     = acc.x;
            op[(2*m + 1) * ST1] = acc.y;
        }
    }
    __syncthreads();

    // fold x4 up-gain AND sqrt2 act-gain into H-up taps; sqrt2 into bias
    const float S42 = 4.0f * 1.41421356237309515f;
    v2f upk2[6];
    #pragma unroll
    for (int j = 0; j < 6; ++j) upk2[j] = upk[j] * S42;
    const float bcs = bc * 1.41421356237309515f;

    // ---- S2: fused H-up + lrelu/clamp + H-down. 252 threads (r 0..41, q 0..5) ----
    // t2p[i] = act( sum_j upk2[j]*{w[i+j]}bcast + {bcs,bcs} ),  i 0..16
    //   act(z) = med3(max(z, 0.2z), -256, 256)   [sqrt2 already in taps/bias]
    // t3[r][12q+oi] = hadd( sum_j gpk[j]*t2p[oi+j] ),  oi 0..11
    // q=5: t1 cols >=74 garbage -> feeds only t3 cols >=64 (pad, never read).
    if (tid < 252) {
        const int r = tid / 6;
        const int q = tid - 6 * r;
        const float* t1r = s_t1 + r * ST1 + 12 * q;
        float w[22];
        #pragma unroll
        for (int j = 0; j < 11; ++j) {
            v2f v2 = *reinterpret_cast<const v2f*>(t1r + 2 * j);
            w[2*j] = v2.x; w[2*j+1] = v2.y;
        }
        const v2f bc2 = bcast2(bcs);
        v2f t2p[17];
        #pragma unroll
        for (int i = 0; i < 17; ++i) {
            v2f acc = bc2;
            #pragma unroll
            for (int j = 0; j < 6; ++j)
                acc = fma2(upk2[j], bcast2(w[i + j]), acc);
            v2f mx = __builtin_elementwise_max(acc, acc * 0.2f);
            t2p[i] = mk2(__builtin_amdgcn_fmed3f(mx.x, -256.0f, 256.0f),
                         __builtin_amdgcn_fmed3f(mx.y, -256.0f, 256.0f));
        }
        float* t3r = s_t3 + r * ST3 + 12 * q;
        #pragma unroll
        for (int i = 0; i < 3; ++i) {
            float4 o4;
            float* op = &o4.x;
            #pragma unroll
            for (int s = 0; s < 4; ++s) {
                const int oi = 4 * i + s;
                v2f acc = gpk[0] * t2p[oi];
                #pragma unroll
                for (int j = 1; j < 6; ++j) acc = fma2(gpk[j], t2p[oi + j], acc);
                op[s] = acc.x + acc.y;
            }
            *reinterpret_cast<float4*>(t3r + 4 * i) = o4;
        }
    }
    __syncthreads();

    // ---- S4: vertical /2 down, 1 col/thread, 256 threads (rc 0..3, c 0..63) ----
    // out rows gy0+4rc..+3 at col c; pairs vp[m] = {t3[8rc+2m][c], t3[8rc+2m+1][c]}
    {
        const int c  = tid & 63;
        const int rc = tid >> 6;
        const float* t3c = s_t3 + (rc << 3) * ST3 + c;
        v2f vp[9];
        #pragma unroll
        for (int m = 0; m < 9; ++m)
            vp[m] = mk2(t3c[(2*m) * ST3], t3c[(2*m + 1) * ST3]);
        float* op = out + ((size_t)nc << 12) + ((size_t)(gy0 + (rc << 2)) << 6) + c;
        #pragma unroll
        for (int i = 0; i < 4; ++i) {
            v2f acc = gpk[0] * vp[i];
            #pragma unroll
            for (int j = 1; j < 6; ++j) acc = fma2(gpk[j], vp[i + j], acc);
            op[(size_t)(i << 6)] = acc.x + acc.y;
        }
    }
}

extern "C" void kernel_launch(void* const* d_in, const int* in_sizes, int n_in,
                              void* d_out, int out_size, void* d_ws, size_t ws_size,
                              hipStream_t stream) {
    const float* x    = (const float*)d_in[0];
    const float* bias = (const float*)d_in[1];
    const float* fu   = (const float*)d_in[2];
    const float* fd   = (const float*)d_in[3];
    float* out        = (float*)d_out;

    dim3 grid(8 * 512 * 4);   // (n*c) x 4 row-tiles of 16x64
    dim3 block(256);
    hipLaunchKernelGGL(synth_fused, grid, block, 0, stream, x, bias, fu, fd, out);
}